// Round 4
// baseline (774.645 us; speedup 1.0000x reference)
//
#include <hip/hip_runtime.h>

#define NN 100000
#define NE 1600000
#define NEG_SLOPE 0.01f

// ---------------------------------------------------------------------------
// Workspace layout (bytes) — total 20,400,384 B (< 25.6 MB proven in round 1).
//   offs : (NN+1) int  @ 0            (400,004)
//   hist : NN int      @ 400,128      (histogram — SEPARATE from cursor)
//   cur  : NN int      @ 800,384      (scatter cursor)
//   perm : NE int      @ 1,200,384    (edge ids grouped by dst, 6.4 MB)
//   hw   : NN*32 float @ 7,600,384    (12.8 MB)
#define OFF_HIST 400128
#define OFF_CUR  800384
#define OFF_PERM 1200384
#define OFF_HW   7600384

#define SB_T 1024
#define SB_C 98       // 1024 * 98 = 100,352 >= NN

// ---------------------------------------------------------------------------
__global__ __launch_bounds__(256) void k_hist(const int* __restrict__ dst,
                                              int* __restrict__ hist)
{
    int e = blockIdx.x * 256 + threadIdx.x;       // grid exact = NE
    atomicAdd(&hist[dst[e]], 1);
}

// Single-block exclusive scan: offs[i] = sum_{k<i} hist[k]; cur[i] = offs[i];
// offs[NN] = NE. One workgroup, 1024 threads, barrier-only coordination.
__global__ __launch_bounds__(SB_T) void k_scan1(const int* __restrict__ hist,
                                                int* __restrict__ offs,
                                                int* __restrict__ cur)
{
    __shared__ int lds[SB_T];
    int t = threadIdx.x;
    int lo = t * SB_C;
    int hi = lo + SB_C; if (hi > NN) hi = NN;
    int s = 0;
    for (int i = lo; i < hi; ++i) s += hist[i];
    lds[t] = s;
    __syncthreads();
    for (int off = 1; off < SB_T; off <<= 1) {     // inclusive scan of totals
        int x = (t >= off) ? lds[t - off] : 0;
        __syncthreads();
        lds[t] += x;
        __syncthreads();
    }
    int run = lds[t] - s;                          // exclusive prefix of chunk
    for (int i = lo; i < hi; ++i) {
        int c = hist[i];                           // read BEFORE any write
        offs[i] = run;
        cur[i] = run;
        run += c;
    }
    if (t == SB_T - 1) offs[NN] = run;             // == NE
}

// perm[pos] = edge id, grouped by dst.
__global__ __launch_bounds__(256) void k_scatter(const int* __restrict__ dst,
                                                 int* __restrict__ cur,
                                                 int* __restrict__ perm)
{
    int e = blockIdx.x * 256 + threadIdx.x;        // grid exact = NE
    int pos = atomicAdd(&cur[dst[e]], 1);
    perm[pos] = e;
}

// ---------------------------------------------------------------------------
// Layer 1 fused: agg (CSR gather, no atomics) + h = lrelu(agg@W1+b1) + hw=h@W2.
// One wave per node, lane = feature. 64 edge records preloaded per batch,
// broadcast per-edge via uniform-index shuffles (fully convergent).
__global__ __launch_bounds__(256) void k_l1(const int* __restrict__ offs,
                                            const int* __restrict__ perm,
                                            const int* __restrict__ esrc,
                                            const float* __restrict__ ew,
                                            const float* __restrict__ feats,
                                            const float* __restrict__ W1,
                                            const float* __restrict__ b1,
                                            const float* __restrict__ W2,
                                            float* __restrict__ hw)
{
    __shared__ float sW1[64][64];
    __shared__ float sW2[64][32];
    __shared__ float sb1[64];
    int tid = threadIdx.x;
    for (int i = tid; i < 64 * 64; i += 256) sW1[i >> 6][i & 63] = W1[i];
    for (int i = tid; i < 64 * 32; i += 256) sW2[i >> 5][i & 31] = W2[i];
    if (tid < 64) sb1[tid] = b1[tid];
    __syncthreads();

    int lane = tid & 63;
    int n = blockIdx.x * 4 + (tid >> 6);           // grid exact = NN waves
    int start = offs[n], end = offs[n + 1];

    float acc = 0.f;
    for (int base = start; base < end; base += 64) {
        int m = end - base; if (m > 64) m = 64;
        int   eid = (lane < m) ? perm[base + lane] : 0;
        int   sv  = (lane < m) ? esrc[eid] : 0;
        float wv  = (lane < m) ? ew[eid] : 0.f;
        for (int j = 0; j < m; ++j) {              // uniform control + index
            int   s = __shfl(sv, j, 64);
            float w = __shfl(wv, j, 64);
            acc = fmaf(w, feats[s * 64 + lane], acc);
        }
    }

    float h = sb1[lane];
    #pragma unroll
    for (int k = 0; k < 64; ++k)
        h = fmaf(__shfl(acc, k, 64), sW1[k][lane], h);
    h = (h >= 0.f) ? h : NEG_SLOPE * h;

    int half = lane >> 5, c = lane & 31;
    float p = 0.f;
    #pragma unroll
    for (int kk = 0; kk < 32; ++kk) {
        int k = (half << 5) + kk;
        p = fmaf(__shfl(h, k, 64), sW2[k][c], p);
    }
    p += __shfl_xor(p, 32, 64);
    if (lane < 32) hw[n * 32 + lane] = p;
}

// ---------------------------------------------------------------------------
// Layer 2: out[n, c] = b2[c] + sum_j w_j * hw[src_j, c]   (F = 32)
// Two edges per iteration; loop bound is WAVE-UNIFORM (m & ~1), every lane
// executes every __shfl (divergent index, convergent execution); only the
// FMA is predicated. Odd tail handled explicitly.
__global__ __launch_bounds__(256) void k_l2(const int* __restrict__ offs,
                                            const int* __restrict__ perm,
                                            const int* __restrict__ esrc,
                                            const float* __restrict__ ew,
                                            const float* __restrict__ hw,
                                            const float* __restrict__ b2,
                                            float* __restrict__ out)
{
    int tid = threadIdx.x;
    int lane = tid & 63;
    int n = blockIdx.x * 4 + (tid >> 6);           // grid exact = NN waves
    int start = offs[n], end = offs[n + 1];
    int half = lane >> 5, c = lane & 31;

    float acc = 0.f;
    for (int base = start; base < end; base += 64) {
        int m = end - base; if (m > 64) m = 64;
        int   eid = (lane < m) ? perm[base + lane] : 0;
        int   sv  = (lane < m) ? esrc[eid] : 0;
        float wv  = (lane < m) ? ew[eid] : 0.f;
        int mm = m & ~1;
        for (int j = 0; j < mm; j += 2) {          // uniform trip count
            int jj = j + half;                     // lanes<32: j, lanes>=32: j+1
            int   s = __shfl(sv, jj, 64);
            float w = __shfl(wv, jj, 64);
            acc = fmaf(w, hw[s * 32 + c], acc);
        }
        if (m & 1) {                               // tail edge m-1
            int   s = __shfl(sv, m - 1, 64);
            float w = __shfl(wv, m - 1, 64);
            if (half == 0) acc = fmaf(w, hw[s * 32 + c], acc);
        }
    }
    acc += __shfl_xor(acc, 32, 64);
    if (lane < 32) out[n * 32 + lane] = acc + b2[lane];
}

// ---------------------------------------------------------------------------
extern "C" void kernel_launch(void* const* d_in, const int* in_sizes, int n_in,
                              void* d_out, int out_size, void* d_ws, size_t ws_size,
                              hipStream_t stream)
{
    const float* feats = (const float*)d_in[0];
    const int*   esrc  = (const int*)d_in[1];
    const int*   edst  = (const int*)d_in[2];
    const float* ew    = (const float*)d_in[3];
    const float* W1    = (const float*)d_in[4];
    const float* b1    = (const float*)d_in[5];
    const float* W2    = (const float*)d_in[6];
    const float* b2    = (const float*)d_in[7];
    float* out = (float*)d_out;

    char*  ws   = (char*)d_ws;
    int*   offs = (int*)ws;
    int*   hist = (int*)(ws + OFF_HIST);
    int*   cur  = (int*)(ws + OFF_CUR);
    int*   perm = (int*)(ws + OFF_PERM);
    float* hw   = (float*)(ws + OFF_HW);

    hipMemsetAsync(hist, 0, NN * sizeof(int), stream);

    k_hist   <<<NE / 256, 256, 0, stream>>>(edst, hist);
    k_scan1  <<<1,        SB_T, 0, stream>>>(hist, offs, cur);
    k_scatter<<<NE / 256, 256, 0, stream>>>(edst, cur, perm);
    k_l1     <<<NN / 4,   256, 0, stream>>>(offs, perm, esrc, ew, feats, W1, b1, W2, hw);
    k_l2     <<<NN / 4,   256, 0, stream>>>(offs, perm, esrc, ew, hw, b2, out);
}

// Round 5
// 636.762 us; speedup vs baseline: 1.2165x; 1.2165x over previous
//
#include <hip/hip_runtime.h>

#define NN 100000
#define NE 1600000
#define NEG_SLOPE 0.01f

// ---------------------------------------------------------------------------
// Workspace layout (bytes) — total 26,000,384 B. ws >= 26.4 MB is PROVEN:
// round 2/3 ran a 26.4 MB layout bit-deterministically (same output as a
// 20.4 MB layout), so the extra tail is real memory.
//   offs : (NN+1) int   @ 0           (400,004 -> pad 400,384)
//   csr  : NE int2      @ 400,384     ((src, w-bits) grouped by dst, 12.8 MB)
//   hw   : NN*32 float  @ 13,200,384  (12.8 MB)
//   hist : NN int       @ 13,200,384  (aliases hw; dead before k_l1 writes hw)
//   cur  : NN int       @ 13,600,768  (aliases hw; dead before k_l1 writes hw)
#define OFF_CSR  400384
#define OFF_HW   13200384
#define OFF_CUR  (OFF_HW + 400384)

#define SB_T 1024
#define SB_C 98       // 1024 * 98 = 100,352 >= NN

// ---------------------------------------------------------------------------
__global__ __launch_bounds__(256) void k_hist(const int* __restrict__ dst,
                                              int* __restrict__ hist)
{
    int e = blockIdx.x * 256 + threadIdx.x;       // grid exact = NE
    atomicAdd(&hist[dst[e]], 1);
}

// Single-block exclusive scan (proven in round 4): offs[i] = prefix, cur = offs.
__global__ __launch_bounds__(SB_T) void k_scan1(const int* __restrict__ hist,
                                                int* __restrict__ offs,
                                                int* __restrict__ cur)
{
    __shared__ int lds[SB_T];
    int t = threadIdx.x;
    int lo = t * SB_C;
    int hi = lo + SB_C; if (hi > NN) hi = NN;
    int s = 0;
    for (int i = lo; i < hi; ++i) s += hist[i];
    lds[t] = s;
    __syncthreads();
    for (int off = 1; off < SB_T; off <<= 1) {
        int x = (t >= off) ? lds[t - off] : 0;
        __syncthreads();
        lds[t] += x;
        __syncthreads();
    }
    int run = lds[t] - s;
    for (int i = lo; i < hi; ++i) {
        int c = hist[i];
        offs[i] = run;
        cur[i] = run;
        run += c;
    }
    if (t == SB_T - 1) offs[NN] = run;
}

// csr[pos] = (src, bits(w)), grouped by dst. Reads fully coalesced.
__global__ __launch_bounds__(256) void k_scatter(const int* __restrict__ dst,
                                                 const int* __restrict__ esrc,
                                                 const float* __restrict__ ew,
                                                 int* __restrict__ cur,
                                                 int2* __restrict__ csr)
{
    int e = blockIdx.x * 256 + threadIdx.x;        // grid exact = NE
    int pos = atomicAdd(&cur[dst[e]], 1);
    csr[pos] = make_int2(esrc[e], __float_as_int(ew[e]));
}

// ---------------------------------------------------------------------------
// Layer 1 fused. One wave per node. Gather phase: lanes = 4 edge-slots x 16
// float4-segments, so each global_load_dwordx4 covers 4 full feats rows
// (4x fewer loads + 4x shorter shfl->load dep chains than scalar layout).
// Partials combined via shfl_xor(16,32); W1 matmul consumes the replicated
// float4 registers directly via shfl(comp, k>>2).
__global__ __launch_bounds__(256) void k_l1(const int* __restrict__ offs,
                                            const int2* __restrict__ csr,
                                            const float* __restrict__ feats,
                                            const float* __restrict__ W1,
                                            const float* __restrict__ b1,
                                            const float* __restrict__ W2,
                                            float* __restrict__ hw)
{
    __shared__ float sW1[64][64];
    __shared__ float sW2[64][32];
    __shared__ float sb1[64];
    int tid = threadIdx.x;
    for (int i = tid; i < 64 * 64; i += 256) sW1[i >> 6][i & 63] = W1[i];
    for (int i = tid; i < 64 * 32; i += 256) sW2[i >> 5][i & 31] = W2[i];
    if (tid < 64) sb1[tid] = b1[tid];
    __syncthreads();

    int lane = tid & 63;
    int n = blockIdx.x * 4 + (tid >> 6);           // grid exact = NN waves
    int start = offs[n], end = offs[n + 1];

    int sub = lane >> 4;          // edge slot 0..3
    int e4  = lane & 15;          // which float4 of the 64-wide row

    float ax = 0.f, ay = 0.f, az = 0.f, aw = 0.f;
    for (int base = start; base < end; base += 64) {
        int m = end - base; if (m > 64) m = 64;
        int2 ed = (lane < m) ? csr[base + lane] : make_int2(0, 0);  // w=0 pad
        int iters = (m + 3) >> 2;
        #pragma unroll 4
        for (int i = 0; i < iters; ++i) {
            int j = (i << 2) + sub;                // edge index, j<=63 always
            int   s = __shfl(ed.x, j, 64);
            float w = __int_as_float(__shfl(ed.y, j, 64));
            const float4 v = *(const float4*)(feats + s * 64 + (e4 << 2));
            ax = fmaf(w, v.x, ax);
            ay = fmaf(w, v.y, ay);
            az = fmaf(w, v.z, az);
            aw = fmaf(w, v.w, aw);
        }
    }
    // combine edge-slot partials (sub groups differ in lane bits 4,5)
    ax += __shfl_xor(ax, 16, 64); ay += __shfl_xor(ay, 16, 64);
    az += __shfl_xor(az, 16, 64); aw += __shfl_xor(aw, 16, 64);
    ax += __shfl_xor(ax, 32, 64); ay += __shfl_xor(ay, 32, 64);
    az += __shfl_xor(az, 32, 64); aw += __shfl_xor(aw, 32, 64);
    // now lane (e4) holds agg[4*e4 .. 4*e4+3], replicated across sub groups

    float h = sb1[lane];
    #pragma unroll
    for (int k = 0; k < 64; ++k) {
        float comp = ((k & 3) == 0) ? ax : ((k & 3) == 1) ? ay
                   : ((k & 3) == 2) ? az : aw;     // static after unroll
        h = fmaf(__shfl(comp, k >> 2, 64), sW1[k][lane], h);
    }
    h = (h >= 0.f) ? h : NEG_SLOPE * h;

    int half = lane >> 5, c = lane & 31;
    float p = 0.f;
    #pragma unroll
    for (int kk = 0; kk < 32; ++kk) {
        int k = (half << 5) + kk;
        p = fmaf(__shfl(h, k, 64), sW2[k][c], p);
    }
    p += __shfl_xor(p, 32, 64);
    if (lane < 32) hw[n * 32 + lane] = p;
}

// ---------------------------------------------------------------------------
// Layer 2: out[n, :] = b2 + sum_j w_j * hw[src_j, :]  (F = 32).
// Lanes = 8 edge-slots x 8 float4-segments: each load covers 8 hw rows.
__global__ __launch_bounds__(256) void k_l2(const int* __restrict__ offs,
                                            const int2* __restrict__ csr,
                                            const float* __restrict__ hw,
                                            const float* __restrict__ b2,
                                            float* __restrict__ out)
{
    int tid = threadIdx.x;
    int lane = tid & 63;
    int n = blockIdx.x * 4 + (tid >> 6);           // grid exact = NN waves
    int start = offs[n], end = offs[n + 1];

    int sub = lane >> 3;          // edge slot 0..7
    int e4  = lane & 7;           // which float4 of the 32-wide row

    float ax = 0.f, ay = 0.f, az = 0.f, aw = 0.f;
    for (int base = start; base < end; base += 64) {
        int m = end - base; if (m > 64) m = 64;
        int2 ed = (lane < m) ? csr[base + lane] : make_int2(0, 0);  // w=0 pad
        int iters = (m + 7) >> 3;
        #pragma unroll 4
        for (int i = 0; i < iters; ++i) {
            int j = (i << 3) + sub;                // edge index, j<=63 always
            int   s = __shfl(ed.x, j, 64);
            float w = __int_as_float(__shfl(ed.y, j, 64));
            const float4 v = *(const float4*)(hw + s * 32 + (e4 << 2));
            ax = fmaf(w, v.x, ax);
            ay = fmaf(w, v.y, ay);
            az = fmaf(w, v.z, az);
            aw = fmaf(w, v.w, aw);
        }
    }
    // combine the 8 edge-slot partials (lane bits 3,4,5)
    ax += __shfl_xor(ax,  8, 64); ay += __shfl_xor(ay,  8, 64);
    az += __shfl_xor(az,  8, 64); aw += __shfl_xor(aw,  8, 64);
    ax += __shfl_xor(ax, 16, 64); ay += __shfl_xor(ay, 16, 64);
    az += __shfl_xor(az, 16, 64); aw += __shfl_xor(aw, 16, 64);
    ax += __shfl_xor(ax, 32, 64); ay += __shfl_xor(ay, 32, 64);
    az += __shfl_xor(az, 32, 64); aw += __shfl_xor(aw, 32, 64);

    if (lane < 8) {
        const float4 bb = *(const float4*)(b2 + (lane << 2));
        float4 o;
        o.x = ax + bb.x; o.y = ay + bb.y; o.z = az + bb.z; o.w = aw + bb.w;
        *(float4*)(out + n * 32 + (lane << 2)) = o;
    }
}

// ---------------------------------------------------------------------------
extern "C" void kernel_launch(void* const* d_in, const int* in_sizes, int n_in,
                              void* d_out, int out_size, void* d_ws, size_t ws_size,
                              hipStream_t stream)
{
    const float* feats = (const float*)d_in[0];
    const int*   esrc  = (const int*)d_in[1];
    const int*   edst  = (const int*)d_in[2];
    const float* ew    = (const float*)d_in[3];
    const float* W1    = (const float*)d_in[4];
    const float* b1    = (const float*)d_in[5];
    const float* W2    = (const float*)d_in[6];
    const float* b2    = (const float*)d_in[7];
    float* out = (float*)d_out;

    char*  ws   = (char*)d_ws;
    int*   offs = (int*)ws;
    int2*  csr  = (int2*)(ws + OFF_CSR);
    float* hw   = (float*)(ws + OFF_HW);
    int*   hist = (int*)(ws + OFF_HW);     // aliases hw; dead before k_l1
    int*   cur  = (int*)(ws + OFF_CUR);    // aliases hw; dead before k_l1

    hipMemsetAsync(hist, 0, NN * sizeof(int), stream);

    k_hist   <<<NE / 256, 256, 0, stream>>>(edst, hist);
    k_scan1  <<<1,        SB_T, 0, stream>>>(hist, offs, cur);
    k_scatter<<<NE / 256, 256, 0, stream>>>(edst, esrc, ew, cur, csr);
    k_l1     <<<NN / 4,   256, 0, stream>>>(offs, csr, feats, W1, b1, W2, hw);
    k_l2     <<<NN / 4,   256, 0, stream>>>(offs, csr, hw, b2, out);
}

// Round 6
// 417.071 us; speedup vs baseline: 1.8573x; 1.5267x over previous
//
#include <hip/hip_runtime.h>

#define NN 100000
#define NE 1600000
#define NEG_SLOPE 0.01f

// ---------------------------------------------------------------------------
// Workspace layout (bytes) — total 26,000,384 B (ws >= 26.4 MB proven: round
// 2/3 ran a 26.4 MB layout deterministically).
//   offs : (NN+1) int   @ 0           (400,004)
//   csr  : NE int2      @ 400,384     ((src, w-bits) grouped by dst, 12.8 MB)
//   hw   : NN*32 float  @ 13,200,384  (12.8 MB)
//   -- aliased into hw region (all dead before k_l1 writes hw):
//   hist : NN int       @ 13,200,384
//   cur  : NN int       @ 13,600,768
//   sums : 98 int       @ 14,000,768
#define OFF_CSR  400384
#define OFF_HW   13200384
#define OFF_CUR  (OFF_HW + 400384)
#define OFF_SUMS (OFF_CUR + 400000)

#define NSUM 98      // ceil(NN / 1024) chunks

// ---------------------------------------------------------------------------
__global__ __launch_bounds__(256) void k_hist(const int* __restrict__ dst,
                                              int* __restrict__ hist)
{
    int e = blockIdx.x * 256 + threadIdx.x;       // grid exact = NE
    atomicAdd(&hist[dst[e]], 1);
}

// Per-chunk sums: sums[b] = sum(hist[b*1024 .. b*1024+1023]), coalesced.
__global__ __launch_bounds__(256) void k_chunks(const int* __restrict__ hist,
                                                int* __restrict__ sums)
{
    __shared__ int lds[256];
    int t = threadIdx.x, b = blockIdx.x;
    int idx = b * 1024 + t * 4;
    int s = 0;
    #pragma unroll
    for (int i = 0; i < 4; ++i) {
        int id = idx + i;
        s += (id < NN) ? hist[id] : 0;
    }
    lds[t] = s;
    __syncthreads();
    for (int off = 128; off > 0; off >>= 1) {
        if (t < off) lds[t] += lds[t + off];
        __syncthreads();
    }
    if (t == 0) sums[b] = lds[0];
}

// Block b: prefix of sums[0..b-1] (serial over 98 L2-hot ints) + block-local
// LDS scan (the double-barrier pattern proven in round 4) -> offs, cur.
__global__ __launch_bounds__(256) void k_scanwrite(const int* __restrict__ hist,
                                                   const int* __restrict__ sums,
                                                   int* __restrict__ offs,
                                                   int* __restrict__ cur)
{
    __shared__ int lds[256];
    __shared__ int s_pref;
    int t = threadIdx.x, b = blockIdx.x;
    if (t == 0) {
        int p = 0;
        for (int i = 0; i < b; ++i) p += sums[i];
        s_pref = p;
    }
    int idx0 = b * 1024 + t * 4;
    int v[4];
    int s = 0;
    #pragma unroll
    for (int i = 0; i < 4; ++i) {
        int id = idx0 + i;
        v[i] = (id < NN) ? hist[id] : 0;
        s += v[i];
    }
    lds[t] = s;
    __syncthreads();                               // also publishes s_pref
    for (int off = 1; off < 256; off <<= 1) {      // inclusive scan (proven)
        int x = (t >= off) ? lds[t - off] : 0;
        __syncthreads();
        lds[t] += x;
        __syncthreads();
    }
    int run = s_pref + lds[t] - s;                 // exclusive global prefix
    #pragma unroll
    for (int i = 0; i < 4; ++i) {
        int id = idx0 + i;
        if (id < NN) { offs[id] = run; cur[id] = run; }
        run += v[i];
    }
    if (b == NSUM - 1 && t == 255) offs[NN] = run; // == NE (tail v's are 0)
}

// csr[pos] = (src, bits(w)), grouped by dst.
__global__ __launch_bounds__(256) void k_scatter(const int* __restrict__ dst,
                                                 const int* __restrict__ esrc,
                                                 const float* __restrict__ ew,
                                                 int* __restrict__ cur,
                                                 int2* __restrict__ csr)
{
    int e = blockIdx.x * 256 + threadIdx.x;        // grid exact = NE
    int pos = atomicAdd(&cur[dst[e]], 1);
    csr[pos] = make_int2(esrc[e], __float_as_int(ew[e]));
}

// ---------------------------------------------------------------------------
// Layer 1 fused (unchanged from round 5). One wave per node; lanes = 4 edge-
// slots x 16 float4-segments; agg + lrelu(agg@W1+b1)@W2 in registers/LDS.
__global__ __launch_bounds__(256) void k_l1(const int* __restrict__ offs,
                                            const int2* __restrict__ csr,
                                            const float* __restrict__ feats,
                                            const float* __restrict__ W1,
                                            const float* __restrict__ b1,
                                            const float* __restrict__ W2,
                                            float* __restrict__ hw)
{
    __shared__ float sW1[64][64];
    __shared__ float sW2[64][32];
    __shared__ float sb1[64];
    int tid = threadIdx.x;
    for (int i = tid; i < 64 * 64; i += 256) sW1[i >> 6][i & 63] = W1[i];
    for (int i = tid; i < 64 * 32; i += 256) sW2[i >> 5][i & 31] = W2[i];
    if (tid < 64) sb1[tid] = b1[tid];
    __syncthreads();

    int lane = tid & 63;
    int n = blockIdx.x * 4 + (tid >> 6);           // grid exact = NN waves
    int start = offs[n], end = offs[n + 1];

    int sub = lane >> 4;          // edge slot 0..3
    int e4  = lane & 15;          // which float4 of the 64-wide row

    float ax = 0.f, ay = 0.f, az = 0.f, aw = 0.f;
    for (int base = start; base < end; base += 64) {
        int m = end - base; if (m > 64) m = 64;
        int2 ed = (lane < m) ? csr[base + lane] : make_int2(0, 0);  // w=0 pad
        int iters = (m + 3) >> 2;
        #pragma unroll 4
        for (int i = 0; i < iters; ++i) {
            int j = (i << 2) + sub;
            int   s = __shfl(ed.x, j, 64);
            float w = __int_as_float(__shfl(ed.y, j, 64));
            const float4 v = *(const float4*)(feats + s * 64 + (e4 << 2));
            ax = fmaf(w, v.x, ax);
            ay = fmaf(w, v.y, ay);
            az = fmaf(w, v.z, az);
            aw = fmaf(w, v.w, aw);
        }
    }
    ax += __shfl_xor(ax, 16, 64); ay += __shfl_xor(ay, 16, 64);
    az += __shfl_xor(az, 16, 64); aw += __shfl_xor(aw, 16, 64);
    ax += __shfl_xor(ax, 32, 64); ay += __shfl_xor(ay, 32, 64);
    az += __shfl_xor(az, 32, 64); aw += __shfl_xor(aw, 32, 64);

    float h = sb1[lane];
    #pragma unroll
    for (int k = 0; k < 64; ++k) {
        float comp = ((k & 3) == 0) ? ax : ((k & 3) == 1) ? ay
                   : ((k & 3) == 2) ? az : aw;
        h = fmaf(__shfl(comp, k >> 2, 64), sW1[k][lane], h);
    }
    h = (h >= 0.f) ? h : NEG_SLOPE * h;

    int half = lane >> 5, c = lane & 31;
    float p = 0.f;
    #pragma unroll
    for (int kk = 0; kk < 32; ++kk) {
        int k = (half << 5) + kk;
        p = fmaf(__shfl(h, k, 64), sW2[k][c], p);
    }
    p += __shfl_xor(p, 32, 64);
    if (lane < 32) hw[n * 32 + lane] = p;
}

// ---------------------------------------------------------------------------
// Layer 2 (unchanged from round 5): lanes = 8 edge-slots x 8 float4-segments.
__global__ __launch_bounds__(256) void k_l2(const int* __restrict__ offs,
                                            const int2* __restrict__ csr,
                                            const float* __restrict__ hw,
                                            const float* __restrict__ b2,
                                            float* __restrict__ out)
{
    int tid = threadIdx.x;
    int lane = tid & 63;
    int n = blockIdx.x * 4 + (tid >> 6);           // grid exact = NN waves
    int start = offs[n], end = offs[n + 1];

    int sub = lane >> 3;          // edge slot 0..7
    int e4  = lane & 7;           // which float4 of the 32-wide row

    float ax = 0.f, ay = 0.f, az = 0.f, aw = 0.f;
    for (int base = start; base < end; base += 64) {
        int m = end - base; if (m > 64) m = 64;
        int2 ed = (lane < m) ? csr[base + lane] : make_int2(0, 0);  // w=0 pad
        int iters = (m + 7) >> 3;
        #pragma unroll 4
        for (int i = 0; i < iters; ++i) {
            int j = (i << 3) + sub;
            int   s = __shfl(ed.x, j, 64);
            float w = __int_as_float(__shfl(ed.y, j, 64));
            const float4 v = *(const float4*)(hw + s * 32 + (e4 << 2));
            ax = fmaf(w, v.x, ax);
            ay = fmaf(w, v.y, ay);
            az = fmaf(w, v.z, az);
            aw = fmaf(w, v.w, aw);
        }
    }
    ax += __shfl_xor(ax,  8, 64); ay += __shfl_xor(ay,  8, 64);
    az += __shfl_xor(az,  8, 64); aw += __shfl_xor(aw,  8, 64);
    ax += __shfl_xor(ax, 16, 64); ay += __shfl_xor(ay, 16, 64);
    az += __shfl_xor(az, 16, 64); aw += __shfl_xor(aw, 16, 64);
    ax += __shfl_xor(ax, 32, 64); ay += __shfl_xor(ay, 32, 64);
    az += __shfl_xor(az, 32, 64); aw += __shfl_xor(aw, 32, 64);

    if (lane < 8) {
        const float4 bb = *(const float4*)(b2 + (lane << 2));
        float4 o;
        o.x = ax + bb.x; o.y = ay + bb.y; o.z = az + bb.z; o.w = aw + bb.w;
        *(float4*)(out + n * 32 + (lane << 2)) = o;
    }
}

// ---------------------------------------------------------------------------
extern "C" void kernel_launch(void* const* d_in, const int* in_sizes, int n_in,
                              void* d_out, int out_size, void* d_ws, size_t ws_size,
                              hipStream_t stream)
{
    const float* feats = (const float*)d_in[0];
    const int*   esrc  = (const int*)d_in[1];
    const int*   edst  = (const int*)d_in[2];
    const float* ew    = (const float*)d_in[3];
    const float* W1    = (const float*)d_in[4];
    const float* b1    = (const float*)d_in[5];
    const float* W2    = (const float*)d_in[6];
    const float* b2    = (const float*)d_in[7];
    float* out = (float*)d_out;

    char*  ws   = (char*)d_ws;
    int*   offs = (int*)ws;
    int2*  csr  = (int2*)(ws + OFF_CSR);
    float* hw   = (float*)(ws + OFF_HW);
    int*   hist = (int*)(ws + OFF_HW);      // aliases hw; dead before k_l1
    int*   cur  = (int*)(ws + OFF_CUR);     // aliases hw; dead before k_l1
    int*   sums = (int*)(ws + OFF_SUMS);    // aliases hw; dead before k_l1

    hipMemsetAsync(hist, 0, NN * sizeof(int), stream);

    k_hist     <<<NE / 256, 256, 0, stream>>>(edst, hist);
    k_chunks   <<<NSUM,     256, 0, stream>>>(hist, sums);
    k_scanwrite<<<NSUM,     256, 0, stream>>>(hist, sums, offs, cur);
    k_scatter  <<<NE / 256, 256, 0, stream>>>(edst, esrc, ew, cur, csr);
    k_l1       <<<NN / 4,   256, 0, stream>>>(offs, csr, feats, W1, b1, W2, hw);
    k_l2       <<<NN / 4,   256, 0, stream>>>(offs, csr, hw, b2, out);
}